// Round 8
// baseline (218.560 us; speedup 1.0000x reference)
//
#include <hip/hip_runtime.h>
#include <hip/hip_bf16.h>
#include <math.h>

#define IN_DIM 128
#define HID 128
#define HEADS 8
#define OUT_DIM 64
#define SLOPE 0.2f
#define BSHIFT 7          // 128 nodes per bucket
#define BCAP 4096         // entries per bucket (mean ~2176)
#define BCAPSHIFT 12
#define EPT 8             // edges per thread in bscatter
#define G1 256            // persistent gemm1 blocks
#define G2 256            // persistent gemm2 blocks

typedef short bf16x8 __attribute__((ext_vector_type(8)));
typedef float f32x4 __attribute__((ext_vector_type(4)));

__device__ __forceinline__ float lrelu(float x) { return fmaxf(x, SLOPE * x); }
__device__ __forceinline__ float bf2f(unsigned u) { return __uint_as_float(u << 16); }
__device__ __forceinline__ unsigned short f2bf(float f) {
    unsigned u = __float_as_uint(f);
    return (unsigned short)((u + 0x7FFF + ((u >> 16) & 1)) >> 16);  // RNE
}

// ---------------- K1 path A: block-aggregated bucket scatter -----------------
__device__ __forceinline__ void bscatter_body(
    int blk, int* smem, const int* __restrict__ idx,
    int* __restrict__ gcursor, unsigned* __restrict__ bucket_buf,
    int E, int N, int NB) {
    int* hist = smem;          // [512]
    int* base = smem + 512;    // [512]
    int* s_nz = smem + 1024;
    int t = threadIdx.x;
    for (int i = t; i < NB; i += 256) hist[i] = 0;
    if (t == 0) *s_nz = 0;
    __syncthreads();
    // inline dtype detection: odd int32 words nonzero => int32 storage
    {
        int nz = (idx[2 * t + 1] != 0) + (idx[2 * t + 513] != 0);
        if (nz) atomicAdd(s_nz, nz);
    }
    __syncthreads();
    int flag = (*s_nz > 16) ? 1 : 0;   // 1 => int32, 0 => int64 storage
    int e0 = blk * (256 * EPT);
    int EN = E + N;
    unsigned ent[EPT];
    int bid[EPT];
    int loc[EPT];
#pragma unroll
    for (int k = 0; k < EPT; k++) {
        int e = e0 + k * 256 + t;
        bid[k] = -1;
        if (e < EN) {
            int src, dst;
            if (e < E) {
                if (flag) { src = idx[e]; dst = idx[E + e]; }
                else      { src = idx[2 * e]; dst = idx[2 * (E + e)]; }
            } else {
                src = dst = e - E;
            }
            int b = dst >> BSHIFT;
            bid[k] = b;
            ent[k] = ((unsigned)(dst & ((1 << BSHIFT) - 1)) << 16) | (unsigned)src;
            loc[k] = atomicAdd(&hist[b], 1);
        }
    }
    __syncthreads();
    for (int i = t; i < NB; i += 256) {
        int c = hist[i];
        if (c) base[i] = atomicAdd(&gcursor[i], c);
    }
    __syncthreads();
#pragma unroll
    for (int k = 0; k < EPT; k++) {
        if (bid[k] >= 0) {
            int pos = base[bid[k]] + loc[k];
            if (pos < BCAP) bucket_buf[((size_t)bid[k] << BCAPSHIFT) + pos] = ent[k];
        }
    }
}

// ---------------- K1 path B: MFMA GEMM1 (persistent, grid-stride) ------------
__device__ __forceinline__ void gemm1_body(
    int blk, short* Wt, const float* __restrict__ x, const float* __restrict__ W1,
    unsigned short* __restrict__ h1g, int N) {
    int t = threadIdx.x;
    for (int id = t; id < 128 * 32; id += 256) {       // stage W1 -> Wt[n][k], pad 136
        int k = id >> 5;
        int n0 = (id & 31) * 4;
        float4 v = *(const float4*)&W1[k * 128 + n0];
        Wt[(n0 + 0) * 136 + k] = (short)f2bf(v.x);
        Wt[(n0 + 1) * 136 + k] = (short)f2bf(v.y);
        Wt[(n0 + 2) * 136 + k] = (short)f2bf(v.z);
        Wt[(n0 + 3) * 136 + k] = (short)f2bf(v.w);
    }
    __syncthreads();
    int wv = t >> 6, lane = t & 63;
    int m = lane & 15, q = lane >> 4;
    int T = (N + 63) >> 6;
    for (int tile = blk; tile < T; tile += G1) {
        int row = tile * 64 + wv * 16 + m;
        f32x4 acc[8];
#pragma unroll
        for (int j = 0; j < 8; j++) acc[j] = (f32x4){0.f, 0.f, 0.f, 0.f};
#pragma unroll
        for (int k0 = 0; k0 < 128; k0 += 32) {
            bf16x8 a = {0, 0, 0, 0, 0, 0, 0, 0};
            if (row < N) {
                const float* xp = &x[(size_t)row * 128 + k0 + q * 8];
                float4 u0 = *(const float4*)xp;
                float4 u1 = *(const float4*)(xp + 4);
                a[0] = (short)f2bf(u0.x); a[1] = (short)f2bf(u0.y);
                a[2] = (short)f2bf(u0.z); a[3] = (short)f2bf(u0.w);
                a[4] = (short)f2bf(u1.x); a[5] = (short)f2bf(u1.y);
                a[6] = (short)f2bf(u1.z); a[7] = (short)f2bf(u1.w);
            }
#pragma unroll
            for (int j = 0; j < 8; j++) {
                bf16x8 b = *(const bf16x8*)&Wt[(j * 16 + m) * 136 + k0 + q * 8];
                acc[j] = __builtin_amdgcn_mfma_f32_16x16x32_bf16(a, b, acc[j], 0, 0, 0);
            }
        }
        int rbase = tile * 64 + wv * 16 + q * 4;
#pragma unroll
        for (int r = 0; r < 4; r++) {
            int rr = rbase + r;
            if (rr < N) {
#pragma unroll
                for (int j = 0; j < 8; j++)
                    h1g[(size_t)rr * 128 + j * 16 + m] = f2bf(acc[j][r]);
            }
        }
    }
}

__global__ __launch_bounds__(256) void k1_kernel(
    const int* __restrict__ idx, int* __restrict__ gcursor,
    unsigned* __restrict__ bucket_buf,
    const float* __restrict__ x, const float* __restrict__ W1,
    unsigned short* __restrict__ h1g, int E, int N, int NB, int GS) {
    __shared__ long long smem[4352];   // union: Wt (34816 B) | bscatter (4.1 KB)
    if ((int)blockIdx.x < GS)
        bscatter_body(blockIdx.x, (int*)smem, idx, gcursor, bucket_buf, E, N, NB);
    else
        gemm1_body(blockIdx.x - GS, (short*)smem, x, W1, h1g, N);
}

// ---------------- K2 path A: per-bucket sort (inline bucket-base scan) -------
__device__ __forceinline__ void bsort_body(
    int b, const int* __restrict__ gcursor, const unsigned* __restrict__ bucket_buf,
    int* __restrict__ row_start, int* __restrict__ sorted_src, int N, int NB) {
    __shared__ int cnt[128];
    __shared__ int cur[128];
    __shared__ int red[4];
    __shared__ int s_w0;
    int t = threadIdx.x;
    if (t < 128) cnt[t] = 0;
    // inline exclusive scan over buckets: bbase = sum_{i<b} min(gcursor[i],BCAP)
    int partial = 0;
    for (int i = t; i < b; i += 256) partial += min(gcursor[i], BCAP);
#pragma unroll
    for (int msk = 32; msk > 0; msk >>= 1) partial += __shfl_xor(partial, msk, 64);
    if ((t & 63) == 0) red[t >> 6] = partial;
    __syncthreads();
    int bbase = red[0] + red[1] + red[2] + red[3];
    int c = min(gcursor[b], BCAP);
    const unsigned* buf = bucket_buf + ((size_t)b << BCAPSHIFT);
    for (int i = t; i < c; i += 256)
        atomicAdd(&cnt[(buf[i] >> 16) & 127], 1);
    __syncthreads();
    int v = (t < 128) ? cnt[t] : 0;
    int lane = t & 63;
    int incl = v;
#pragma unroll
    for (int off = 1; off < 64; off <<= 1) {
        int u = __shfl_up(incl, off, 64);
        if (lane >= off) incl += u;
    }
    if (t == 63) s_w0 = incl;
    __syncthreads();
    if (t < 128) {
        int excl = incl - v + ((t >= 64) ? s_w0 : 0);
        int pos = bbase + excl;
        cur[t] = pos;
        int node = (b << BSHIFT) + t;
        if (node <= N) row_start[node] = pos;
    }
    __syncthreads();
    for (int i = t; i < c; i += 256) {
        unsigned e = buf[i];
        int pos = atomicAdd(&cur[(e >> 16) & 127], 1);
        sorted_src[pos] = (int)(e & 0xFFFFu);
    }
}

// ---------------- K2 path B: alpha1 ------------------------------------------
__device__ __forceinline__ void alpha1_body(
    int blk, const unsigned short* __restrict__ h1g,
    const float* __restrict__ a_s, const float* __restrict__ a_d,
    float* __restrict__ as_n, float* __restrict__ ad_n, int N) {
    int gid = blk * 256 + threadIdx.x;
    if (gid >= N * 8) return;
    int n = gid >> 3, hd = gid & 7;
    const uint4* hp = (const uint4*)(h1g + (size_t)n * 128 + hd * 16);
    uint4 u0 = hp[0], u1 = hp[1];
    unsigned uu[8] = {u0.x, u0.y, u0.z, u0.w, u1.x, u1.y, u1.z, u1.w};
    const float* sp = a_s + hd * 16;
    const float* dp = a_d + hd * 16;
    float s = 0.f, d = 0.f;
#pragma unroll
    for (int k = 0; k < 8; k++) {
        float lo = bf2f(uu[k] & 0xffffu), hi = bf2f(uu[k] >> 16);
        s += lo * sp[2 * k] + hi * sp[2 * k + 1];
        d += lo * dp[2 * k] + hi * dp[2 * k + 1];
    }
    as_n[gid] = s;
    ad_n[gid] = d;
}

__global__ __launch_bounds__(256) void k2_kernel(
    const int* __restrict__ gcursor, const unsigned* __restrict__ bucket_buf,
    int* __restrict__ row_start, int* __restrict__ sorted_src,
    const unsigned short* __restrict__ h1g,
    const float* __restrict__ a_s, const float* __restrict__ a_d,
    float* __restrict__ as_n, float* __restrict__ ad_n, int N, int NB, int EN) {
    if (blockIdx.x == 0 && threadIdx.x < 8) sorted_src[EN + threadIdx.x] = 0;  // pad
    if ((int)blockIdx.x < NB)
        bsort_body(blockIdx.x, gcursor, bucket_buf, row_start, sorted_src, N, NB);
    else
        alpha1_body(blockIdx.x - NB, h1g, a_s, a_d, as_n, ad_n, N);
}

// ---------------- layer-1 aggregation: wave/node, 8 edges/iter ---------------
// Weight role: lane = edge(lane>>3) x head(lane&7) -> 64 unique (e,h) weights.
// Gather role: lane = slot(2b) x cg(4b); weights+src indices arrive via shfl.
__global__ __launch_bounds__(256) void agg1_kernel(
    const int* __restrict__ row_start, const int* __restrict__ sorted_src,
    const float* __restrict__ as_n, const float* __restrict__ ad_n,
    const unsigned short* __restrict__ h1g, const float* __restrict__ b1,
    unsigned short* __restrict__ h1act, int N) {
    int node = blockIdx.x * 4 + (threadIdx.x >> 6);
    int lane = threadIdx.x & 63;
    if (node >= N) return;
    int slot = lane >> 4, cg = lane & 15;
    int e8 = lane >> 3, hd8 = lane & 7;
    int wl_a = (slot << 3) | (cg >> 1);          // lane holding edge i+slot, my head
    int wl_b = ((slot + 4) << 3) | (cg >> 1);    // lane holding edge i+slot+4
    float ad_w = ad_n[node * 8 + hd8];
    int beg = row_start[node], end = row_start[node + 1];
    float acc[8];
#pragma unroll
    for (int k = 0; k < 8; k++) acc[k] = 0.f;
    float denom = 0.f;
    for (int i = beg; i < end; i += 8) {
        int se = sorted_src[i + e8];             // padded: no clamp needed
        float w = __expf(lrelu(as_n[se * 8 + hd8] + ad_w));
        w = (i + e8 < end) ? w : 0.f;
        float wva = __shfl(w, wl_a, 64);
        float wvb = __shfl(w, wl_b, 64);
        int sga = __shfl(se, wl_a, 64);
        int sgb = __shfl(se, wl_b, 64);
        uint4 hva = *(const uint4*)&h1g[(size_t)sga * 128 + cg * 8];
        uint4 hvb = *(const uint4*)&h1g[(size_t)sgb * 128 + cg * 8];
        acc[0] += wva * bf2f(hva.x & 0xffffu) + wvb * bf2f(hvb.x & 0xffffu);
        acc[1] += wva * bf2f(hva.x >> 16)     + wvb * bf2f(hvb.x >> 16);
        acc[2] += wva * bf2f(hva.y & 0xffffu) + wvb * bf2f(hvb.y & 0xffffu);
        acc[3] += wva * bf2f(hva.y >> 16)     + wvb * bf2f(hvb.y >> 16);
        acc[4] += wva * bf2f(hva.z & 0xffffu) + wvb * bf2f(hvb.z & 0xffffu);
        acc[5] += wva * bf2f(hva.z >> 16)     + wvb * bf2f(hvb.z >> 16);
        acc[6] += wva * bf2f(hva.w & 0xffffu) + wvb * bf2f(hvb.w & 0xffffu);
        acc[7] += wva * bf2f(hva.w >> 16)     + wvb * bf2f(hvb.w >> 16);
        denom += wva + wvb;
    }
    // reduce over the 4 slots (lane bits 4-5)
#pragma unroll
    for (int msk = 16; msk < 64; msk <<= 1) {
#pragma unroll
        for (int k = 0; k < 8; k++) acc[k] += __shfl_xor(acc[k], msk, 64);
        denom += __shfl_xor(denom, msk, 64);
    }
    if (slot == 0) {
        float inv = 1.f / (denom + 1e-16f);
        int c0 = cg * 8;
        unsigned ow[4];
#pragma unroll
        for (int p = 0; p < 4; p++) {
            float v0 = acc[2 * p] * inv + b1[c0 + 2 * p];
            float v1 = acc[2 * p + 1] * inv + b1[c0 + 2 * p + 1];
            v0 = (v0 > 0.f) ? v0 : (__expf(v0) - 1.f);
            v1 = (v1 > 0.f) ? v1 : (__expf(v1) - 1.f);
            ow[p] = (unsigned)f2bf(v0) | ((unsigned)f2bf(v1) << 16);
        }
        *(uint4*)&h1act[(size_t)node * 128 + c0] = make_uint4(ow[0], ow[1], ow[2], ow[3]);
    }
}

// ---------------- GEMM2 (MFMA, persistent) + fused alpha2 --------------------
__global__ __launch_bounds__(256) void gemm2_kernel(
    const unsigned short* __restrict__ h1act, const float* __restrict__ W2,
    const float* __restrict__ a_s, const float* __restrict__ a_d,
    unsigned short* __restrict__ h2g, float* __restrict__ as_n,
    float* __restrict__ ad_n, int N) {
    __shared__ short Wt[64 * 136];
    int t = threadIdx.x;
    for (int id = t; id < 128 * 16; id += 256) {
        int k = id >> 4;
        int n0 = (id & 15) * 4;
        float4 v = *(const float4*)&W2[k * 64 + n0];
        Wt[(n0 + 0) * 136 + k] = (short)f2bf(v.x);
        Wt[(n0 + 1) * 136 + k] = (short)f2bf(v.y);
        Wt[(n0 + 2) * 136 + k] = (short)f2bf(v.z);
        Wt[(n0 + 3) * 136 + k] = (short)f2bf(v.w);
    }
    __syncthreads();
    int wv = t >> 6, lane = t & 63;
    int m = lane & 15, q = lane >> 4;
    float asl[4], adl[4];
#pragma unroll
    for (int j = 0; j < 4; j++) { asl[j] = a_s[j * 16 + m]; adl[j] = a_d[j * 16 + m]; }
    int T = (N + 63) >> 6;
    for (int tile = blockIdx.x; tile < T; tile += G2) {
        int row = tile * 64 + wv * 16 + m;
        f32x4 acc[4];
#pragma unroll
        for (int j = 0; j < 4; j++) acc[j] = (f32x4){0.f, 0.f, 0.f, 0.f};
#pragma unroll
        for (int k0 = 0; k0 < 128; k0 += 32) {
            bf16x8 a = {0, 0, 0, 0, 0, 0, 0, 0};
            if (row < N) a = *(const bf16x8*)&h1act[(size_t)row * 128 + k0 + q * 8];
#pragma unroll
            for (int j = 0; j < 4; j++) {
                bf16x8 b = *(const bf16x8*)&Wt[(j * 16 + m) * 136 + k0 + q * 8];
                acc[j] = __builtin_amdgcn_mfma_f32_16x16x32_bf16(a, b, acc[j], 0, 0, 0);
            }
        }
        int rbase = tile * 64 + wv * 16 + q * 4;
#pragma unroll
        for (int r = 0; r < 4; r++) {
            int rr = rbase + r;
            float s = 0.f, d = 0.f;
#pragma unroll
            for (int j = 0; j < 4; j++) {
                s += acc[j][r] * asl[j];
                d += acc[j][r] * adl[j];
            }
#pragma unroll
            for (int msk = 8; msk > 0; msk >>= 1) {
                s += __shfl_xor(s, msk, 64);
                d += __shfl_xor(d, msk, 64);
            }
            if (rr < N) {
                if (m == 0) { as_n[rr] = s; ad_n[rr] = d; }
#pragma unroll
                for (int j = 0; j < 4; j++)
                    h2g[(size_t)rr * 64 + j * 16 + m] = f2bf(acc[j][r]);
            }
        }
    }
}

// ---------------- layer-2 aggregation + log_softmax: wave/node ---------------
__global__ __launch_bounds__(256) void agg2_kernel(
    const int* __restrict__ row_start, const int* __restrict__ sorted_src,
    const float* __restrict__ as_n, const float* __restrict__ ad_n,
    const unsigned short* __restrict__ h2g, const float* __restrict__ b2,
    float* __restrict__ out, int N) {
    int node = blockIdx.x * 4 + (threadIdx.x >> 6);
    int lane = threadIdx.x & 63;
    if (node >= N) return;
    int slot = lane >> 4, cg = lane & 15;
    int e8 = lane & 7;
    float adv = ad_n[node];
    int beg = row_start[node], end = row_start[node + 1];
    float acc[4];
#pragma unroll
    for (int k = 0; k < 4; k++) acc[k] = 0.f;
    float denom = 0.f;
    for (int i = beg; i < end; i += 8) {
        int se = sorted_src[i + e8];             // padded: no clamp
        float w = __expf(lrelu(as_n[se] + adv));
        w = (i + e8 < end) ? w : 0.f;
        float wva = __shfl(w, slot, 64);
        float wvb = __shfl(w, slot + 4, 64);
        int sga = __shfl(se, slot, 64);
        int sgb = __shfl(se, slot + 4, 64);
        uint2 hva = *(const uint2*)&h2g[(size_t)sga * 64 + cg * 4];
        uint2 hvb = *(const uint2*)&h2g[(size_t)sgb * 64 + cg * 4];
        acc[0] += wva * bf2f(hva.x & 0xffffu) + wvb * bf2f(hvb.x & 0xffffu);
        acc[1] += wva * bf2f(hva.x >> 16)     + wvb * bf2f(hvb.x >> 16);
        acc[2] += wva * bf2f(hva.y & 0xffffu) + wvb * bf2f(hvb.y & 0xffffu);
        acc[3] += wva * bf2f(hva.y >> 16)     + wvb * bf2f(hvb.y >> 16);
        denom += wva + wvb;
    }
#pragma unroll
    for (int msk = 16; msk < 64; msk <<= 1) {
#pragma unroll
        for (int k = 0; k < 4; k++) acc[k] += __shfl_xor(acc[k], msk, 64);
        denom += __shfl_xor(denom, msk, 64);
    }
    if (slot == 0) {
        float inv = 1.f / (denom + 1e-16f);
        int c0 = cg * 4;
        float v[4];
#pragma unroll
        for (int k = 0; k < 4; k++) v[k] = acc[k] * inv + b2[c0 + k];
        float m = fmaxf(fmaxf(v[0], v[1]), fmaxf(v[2], v[3]));
#pragma unroll
        for (int msk = 8; msk > 0; msk >>= 1) m = fmaxf(m, __shfl_xor(m, msk, 64));
        float ex = __expf(v[0] - m) + __expf(v[1] - m) + __expf(v[2] - m) + __expf(v[3] - m);
#pragma unroll
        for (int msk = 8; msk > 0; msk >>= 1) ex += __shfl_xor(ex, msk, 64);
        float lse = m + __logf(ex);
        float4 ov = make_float4(v[0] - lse, v[1] - lse, v[2] - lse, v[3] - lse);
        *(float4*)&out[(size_t)node * 64 + c0] = ov;
    }
}

extern "C" void kernel_launch(void* const* d_in, const int* in_sizes, int n_in,
                              void* d_out, int out_size, void* d_ws, size_t ws_size,
                              hipStream_t stream) {
    const float* x   = (const float*)d_in[0];
    const int*   idx = (const int*)d_in[1];
    const float* W1  = (const float*)d_in[2];
    const float* as1 = (const float*)d_in[3];
    const float* ad1 = (const float*)d_in[4];
    const float* b1  = (const float*)d_in[5];
    const float* W2  = (const float*)d_in[6];
    const float* as2 = (const float*)d_in[7];
    const float* ad2 = (const float*)d_in[8];
    const float* b2  = (const float*)d_in[9];
    float* out = (float*)d_out;

    const int N = in_sizes[0] / IN_DIM;
    const int E = in_sizes[1] / 2;
    const int EN = E + N;
    const int NB = (N + (1 << BSHIFT) - 1) >> BSHIFT;   // buckets
    const int GS = (EN + 256 * EPT - 1) / (256 * EPT);  // bscatter blocks
    const int A1 = (N * 8 + 255) / 256;                  // alpha1 blocks

    // workspace layout
    unsigned short* h1g   = (unsigned short*)d_ws;          // N*128 bf16
    unsigned short* h1act = h1g + (size_t)N * 128;          // N*128 bf16
    unsigned short* h2g   = h1act + (size_t)N * 128;        // N*64 bf16
    float* as1n = (float*)(h2g + (size_t)N * 64);           // N*8
    float* ad1n = as1n + (size_t)N * 8;                     // N*8
    float* as2n = ad1n + (size_t)N * 8;                     // N
    float* ad2n = as2n + (size_t)N;                         // N
    int* row_start  = (int*)(ad2n + (size_t)N);             // N+1
    int* gcursor    = row_start + N + 1;                    // 512
    unsigned* bucket_buf = (unsigned*)(gcursor + 512);      // NB*BCAP
    int* sorted_src = (int*)(bucket_buf + ((size_t)NB << BCAPSHIFT));  // E+N+8 (padded)
    (void)ws_size; (void)n_in; (void)out_size;

    hipMemsetAsync(gcursor, 0, 512 * sizeof(int), stream);

    k1_kernel<<<GS + G1, 256, 0, stream>>>(idx, gcursor, bucket_buf,
                                           x, W1, h1g, E, N, NB, GS);
    k2_kernel<<<NB + A1, 256, 0, stream>>>(gcursor, bucket_buf, row_start, sorted_src,
                                           h1g, as1, ad1, as1n, ad1n, N, NB, EN);
    agg1_kernel<<<(N + 3) / 4, 256, 0, stream>>>(row_start, sorted_src, as1n, ad1n, h1g, b1, h1act, N);
    gemm2_kernel<<<G2, 256, 0, stream>>>(h1act, W2, as2, ad2, h2g, as2n, ad2n, N);
    agg2_kernel<<<(N + 3) / 4, 256, 0, stream>>>(row_start, sorted_src, as2n, ad2n, h2g, b2, out, N);
}

// Round 9
// 215.798 us; speedup vs baseline: 1.0128x; 1.0128x over previous
//
#include <hip/hip_runtime.h>
#include <hip/hip_bf16.h>
#include <math.h>

#define IN_DIM 128
#define HID 128
#define HEADS 8
#define OUT_DIM 64
#define SLOPE 0.2f
#define BSHIFT 7          // 128 nodes per bucket
#define BCAP 4096         // entries per bucket (mean ~2176)
#define BCAPSHIFT 12
#define EPT 8             // edges per thread in bscatter
#define G1 256            // persistent gemm1 blocks
#define G2 256            // persistent gemm2 blocks

typedef short bf16x8 __attribute__((ext_vector_type(8)));
typedef float f32x4 __attribute__((ext_vector_type(4)));

__device__ __forceinline__ float lrelu(float x) { return fmaxf(x, SLOPE * x); }
__device__ __forceinline__ float bf2f(unsigned u) { return __uint_as_float(u << 16); }
__device__ __forceinline__ unsigned short f2bf(float f) {
    unsigned u = __float_as_uint(f);
    return (unsigned short)((u + 0x7FFF + ((u >> 16) & 1)) >> 16);  // RNE
}

// ---------------- K1 path A: bucket scatter with block-local counting sort ---
// LDS layout (ints): hist[512] | gbase[512] | lbase[512] | wtot[4] | misc[2]
//                    sent[2048] | spos[2048]   -> 5648 ints = 22.6 KB
__device__ __forceinline__ void bscatter_body(
    int blk, int* smem, const int* __restrict__ idx,
    int* __restrict__ gcursor, unsigned* __restrict__ bucket_buf,
    int E, int N, int NB) {
    int* hist  = smem;
    int* gbase = smem + 512;
    int* lbase = smem + 1024;
    int* wtot  = smem + 1536;
    int* misc  = smem + 1540;     // [0]=total, [1]=nz
    unsigned* sent = (unsigned*)(smem + 1552);
    unsigned* spos = (unsigned*)(smem + 3600);
    int t = threadIdx.x;
    for (int i = t; i < 512; i += 256) hist[i] = 0;
    if (t == 0) misc[1] = 0;
    __syncthreads();
    // inline dtype detection: odd int32 words nonzero => int32 storage
    {
        int nz = (idx[2 * t + 1] != 0) + (idx[2 * t + 513] != 0);
        if (nz) atomicAdd(&misc[1], nz);
    }
    __syncthreads();
    int flag = (misc[1] > 16) ? 1 : 0;   // 1 => int32, 0 => int64 storage
    int e0 = blk * (256 * EPT);
    int EN = E + N;
    unsigned ent[EPT];
    int bid[EPT];
    int loc[EPT];
#pragma unroll
    for (int k = 0; k < EPT; k++) {
        int e = e0 + k * 256 + t;
        bid[k] = -1;
        if (e < EN) {
            int src, dst;
            if (e < E) {
                if (flag) { src = idx[e]; dst = idx[E + e]; }
                else      { src = idx[2 * e]; dst = idx[2 * (E + e)]; }
            } else {
                src = dst = e - E;
            }
            int b = dst >> BSHIFT;
            bid[k] = b;
            ent[k] = ((unsigned)(dst & ((1 << BSHIFT) - 1)) << 16) | (unsigned)src;
            loc[k] = atomicAdd(&hist[b], 1);
        }
    }
    __syncthreads();
    // exclusive scan of hist[0..512) : 256 threads x 2 consecutive elements
    int i0 = 2 * t;
    int a = hist[i0], b2 = hist[i0 + 1];
    int ps = a + b2;
    int lane = t & 63, w = t >> 6;
    int incl = ps;
#pragma unroll
    for (int off = 1; off < 64; off <<= 1) {
        int u = __shfl_up(incl, off, 64);
        if (lane >= off) incl += u;
    }
    if (lane == 63) wtot[w] = incl;
    __syncthreads();
    int woff = 0;
    for (int k = 0; k < w; k++) woff += wtot[k];
    int ex0 = woff + incl - ps;
    lbase[i0] = ex0;
    lbase[i0 + 1] = ex0 + a;
    if (t == 255) misc[0] = woff + incl;   // total entries this block
    // reserve global chunks (one atomic per non-empty bucket)
    for (int i = t; i < 512; i += 256) {
        int c = hist[i];
        gbase[i] = c ? atomicAdd(&gcursor[i], c) : 0;
    }
    __syncthreads();
    // stage entries in bucket-sorted order with their global positions
#pragma unroll
    for (int k = 0; k < EPT; k++) {
        if (bid[k] >= 0) {
            int p = lbase[bid[k]] + loc[k];
            int pib = gbase[bid[k]] + loc[k];
            sent[p] = ent[k];
            spos[p] = (pib < BCAP) ? (((unsigned)bid[k] << BCAPSHIFT) | (unsigned)pib)
                                   : 0xFFFFFFFFu;
        }
    }
    __syncthreads();
    // flush: consecutive i -> consecutive positions within bucket runs
    int tot = misc[0];
    for (int i = t; i < tot; i += 256) {
        unsigned sp = spos[i];
        if (sp != 0xFFFFFFFFu) bucket_buf[sp] = sent[i];
    }
}

// ---------------- K1 path B: MFMA GEMM1 (persistent, grid-stride) ------------
__device__ __forceinline__ void gemm1_body(
    int blk, short* Wt, const float* __restrict__ x, const float* __restrict__ W1,
    unsigned short* __restrict__ h1g, int N) {
    int t = threadIdx.x;
    for (int id = t; id < 128 * 32; id += 256) {       // stage W1 -> Wt[n][k], pad 136
        int k = id >> 5;
        int n0 = (id & 31) * 4;
        float4 v = *(const float4*)&W1[k * 128 + n0];
        Wt[(n0 + 0) * 136 + k] = (short)f2bf(v.x);
        Wt[(n0 + 1) * 136 + k] = (short)f2bf(v.y);
        Wt[(n0 + 2) * 136 + k] = (short)f2bf(v.z);
        Wt[(n0 + 3) * 136 + k] = (short)f2bf(v.w);
    }
    __syncthreads();
    int wv = t >> 6, lane = t & 63;
    int m = lane & 15, q = lane >> 4;
    int T = (N + 63) >> 6;
    for (int tile = blk; tile < T; tile += G1) {
        int row = tile * 64 + wv * 16 + m;
        f32x4 acc[8];
#pragma unroll
        for (int j = 0; j < 8; j++) acc[j] = (f32x4){0.f, 0.f, 0.f, 0.f};
#pragma unroll
        for (int k0 = 0; k0 < 128; k0 += 32) {
            bf16x8 a = {0, 0, 0, 0, 0, 0, 0, 0};
            if (row < N) {
                const float* xp = &x[(size_t)row * 128 + k0 + q * 8];
                float4 u0 = *(const float4*)xp;
                float4 u1 = *(const float4*)(xp + 4);
                a[0] = (short)f2bf(u0.x); a[1] = (short)f2bf(u0.y);
                a[2] = (short)f2bf(u0.z); a[3] = (short)f2bf(u0.w);
                a[4] = (short)f2bf(u1.x); a[5] = (short)f2bf(u1.y);
                a[6] = (short)f2bf(u1.z); a[7] = (short)f2bf(u1.w);
            }
#pragma unroll
            for (int j = 0; j < 8; j++) {
                bf16x8 b = *(const bf16x8*)&Wt[(j * 16 + m) * 136 + k0 + q * 8];
                acc[j] = __builtin_amdgcn_mfma_f32_16x16x32_bf16(a, b, acc[j], 0, 0, 0);
            }
        }
        int rbase = tile * 64 + wv * 16 + q * 4;
#pragma unroll
        for (int r = 0; r < 4; r++) {
            int rr = rbase + r;
            if (rr < N) {
#pragma unroll
                for (int j = 0; j < 8; j++)
                    h1g[(size_t)rr * 128 + j * 16 + m] = f2bf(acc[j][r]);
            }
        }
    }
}

__global__ __launch_bounds__(256) void k1_kernel(
    const int* __restrict__ idx, int* __restrict__ gcursor,
    unsigned* __restrict__ bucket_buf,
    const float* __restrict__ x, const float* __restrict__ W1,
    unsigned short* __restrict__ h1g, int E, int N, int NB, int GS) {
    __shared__ long long smem[4352];   // union: Wt (34816 B) | bscatter (22.6 KB)
    if ((int)blockIdx.x < GS)
        bscatter_body(blockIdx.x, (int*)smem, idx, gcursor, bucket_buf, E, N, NB);
    else
        gemm1_body(blockIdx.x - GS, (short*)smem, x, W1, h1g, N);
}

// ---------------- K2 path A: per-bucket sort, LDS-staged coalesced flush -----
__device__ __forceinline__ void bsort_body(
    int b, const int* __restrict__ gcursor, const unsigned* __restrict__ bucket_buf,
    int* __restrict__ row_start, int* __restrict__ sorted_src, int N, int NB) {
    __shared__ int cnt[128];
    __shared__ int cur[128];
    __shared__ int red[4];
    __shared__ int s_w0;
    __shared__ int srt[BCAP];
    int t = threadIdx.x;
    if (t < 128) cnt[t] = 0;
    // inline exclusive scan over buckets: bbase = sum_{i<b} min(gcursor[i],BCAP)
    int partial = 0;
    for (int i = t; i < b; i += 256) partial += min(gcursor[i], BCAP);
#pragma unroll
    for (int msk = 32; msk > 0; msk >>= 1) partial += __shfl_xor(partial, msk, 64);
    if ((t & 63) == 0) red[t >> 6] = partial;
    __syncthreads();
    int bbase = red[0] + red[1] + red[2] + red[3];
    int c = min(gcursor[b], BCAP);
    const unsigned* buf = bucket_buf + ((size_t)b << BCAPSHIFT);
    for (int i = t; i < c; i += 256)
        atomicAdd(&cnt[(buf[i] >> 16) & 127], 1);
    __syncthreads();
    int v = (t < 128) ? cnt[t] : 0;
    int lane = t & 63;
    int incl = v;
#pragma unroll
    for (int off = 1; off < 64; off <<= 1) {
        int u = __shfl_up(incl, off, 64);
        if (lane >= off) incl += u;
    }
    if (t == 63) s_w0 = incl;
    __syncthreads();
    if (t < 128) {
        int excl = incl - v + ((t >= 64) ? s_w0 : 0);
        cur[t] = excl;                      // LOCAL position within bucket
        int node = (b << BSHIFT) + t;
        if (node <= N) row_start[node] = bbase + excl;
    }
    __syncthreads();
    for (int i = t; i < c; i += 256) {
        unsigned e = buf[i];
        int lp = atomicAdd(&cur[(e >> 16) & 127], 1);
        srt[lp] = (int)(e & 0xFFFFu);
    }
    __syncthreads();
    for (int i = t; i < c; i += 256)
        sorted_src[bbase + i] = srt[i];     // coalesced flush
}

// ---------------- K2 path B: alpha1 ------------------------------------------
__device__ __forceinline__ void alpha1_body(
    int blk, const unsigned short* __restrict__ h1g,
    const float* __restrict__ a_s, const float* __restrict__ a_d,
    float* __restrict__ as_n, float* __restrict__ ad_n, int N) {
    int gid = blk * 256 + threadIdx.x;
    if (gid >= N * 8) return;
    int n = gid >> 3, hd = gid & 7;
    const uint4* hp = (const uint4*)(h1g + (size_t)n * 128 + hd * 16);
    uint4 u0 = hp[0], u1 = hp[1];
    unsigned uu[8] = {u0.x, u0.y, u0.z, u0.w, u1.x, u1.y, u1.z, u1.w};
    const float* sp = a_s + hd * 16;
    const float* dp = a_d + hd * 16;
    float s = 0.f, d = 0.f;
#pragma unroll
    for (int k = 0; k < 8; k++) {
        float lo = bf2f(uu[k] & 0xffffu), hi = bf2f(uu[k] >> 16);
        s += lo * sp[2 * k] + hi * sp[2 * k + 1];
        d += lo * dp[2 * k] + hi * dp[2 * k + 1];
    }
    as_n[gid] = s;
    ad_n[gid] = d;
}

__global__ __launch_bounds__(256) void k2_kernel(
    const int* __restrict__ gcursor, const unsigned* __restrict__ bucket_buf,
    int* __restrict__ row_start, int* __restrict__ sorted_src,
    const unsigned short* __restrict__ h1g,
    const float* __restrict__ a_s, const float* __restrict__ a_d,
    float* __restrict__ as_n, float* __restrict__ ad_n, int N, int NB, int EN) {
    if (blockIdx.x == 0 && threadIdx.x < 8) sorted_src[EN + threadIdx.x] = 0;  // pad
    if ((int)blockIdx.x < NB)
        bsort_body(blockIdx.x, gcursor, bucket_buf, row_start, sorted_src, N, NB);
    else
        alpha1_body(blockIdx.x - NB, h1g, a_s, a_d, as_n, ad_n, N);
}

// ---------------- layer-1 aggregation: wave/node, 8 edges/iter ---------------
__global__ __launch_bounds__(256) void agg1_kernel(
    const int* __restrict__ row_start, const int* __restrict__ sorted_src,
    const float* __restrict__ as_n, const float* __restrict__ ad_n,
    const unsigned short* __restrict__ h1g, const float* __restrict__ b1,
    unsigned short* __restrict__ h1act, int N) {
    int node = blockIdx.x * 4 + (threadIdx.x >> 6);
    int lane = threadIdx.x & 63;
    if (node >= N) return;
    int slot = lane >> 4, cg = lane & 15;
    int e8 = lane >> 3, hd8 = lane & 7;
    int wl_a = (slot << 3) | (cg >> 1);
    int wl_b = ((slot + 4) << 3) | (cg >> 1);
    float ad_w = ad_n[node * 8 + hd8];
    int beg = row_start[node], end = row_start[node + 1];
    float acc[8];
#pragma unroll
    for (int k = 0; k < 8; k++) acc[k] = 0.f;
    float denom = 0.f;
    for (int i = beg; i < end; i += 8) {
        int se = sorted_src[i + e8];
        float w = __expf(lrelu(as_n[se * 8 + hd8] + ad_w));
        w = (i + e8 < end) ? w : 0.f;
        float wva = __shfl(w, wl_a, 64);
        float wvb = __shfl(w, wl_b, 64);
        int sga = __shfl(se, wl_a, 64);
        int sgb = __shfl(se, wl_b, 64);
        uint4 hva = *(const uint4*)&h1g[(size_t)sga * 128 + cg * 8];
        uint4 hvb = *(const uint4*)&h1g[(size_t)sgb * 128 + cg * 8];
        acc[0] += wva * bf2f(hva.x & 0xffffu) + wvb * bf2f(hvb.x & 0xffffu);
        acc[1] += wva * bf2f(hva.x >> 16)     + wvb * bf2f(hvb.x >> 16);
        acc[2] += wva * bf2f(hva.y & 0xffffu) + wvb * bf2f(hvb.y & 0xffffu);
        acc[3] += wva * bf2f(hva.y >> 16)     + wvb * bf2f(hvb.y >> 16);
        acc[4] += wva * bf2f(hva.z & 0xffffu) + wvb * bf2f(hvb.z & 0xffffu);
        acc[5] += wva * bf2f(hva.z >> 16)     + wvb * bf2f(hvb.z >> 16);
        acc[6] += wva * bf2f(hva.w & 0xffffu) + wvb * bf2f(hvb.w & 0xffffu);
        acc[7] += wva * bf2f(hva.w >> 16)     + wvb * bf2f(hvb.w >> 16);
        denom += wva + wvb;
    }
#pragma unroll
    for (int msk = 16; msk < 64; msk <<= 1) {
#pragma unroll
        for (int k = 0; k < 8; k++) acc[k] += __shfl_xor(acc[k], msk, 64);
        denom += __shfl_xor(denom, msk, 64);
    }
    if (slot == 0) {
        float inv = 1.f / (denom + 1e-16f);
        int c0 = cg * 8;
        unsigned ow[4];
#pragma unroll
        for (int p = 0; p < 4; p++) {
            float v0 = acc[2 * p] * inv + b1[c0 + 2 * p];
            float v1 = acc[2 * p + 1] * inv + b1[c0 + 2 * p + 1];
            v0 = (v0 > 0.f) ? v0 : (__expf(v0) - 1.f);
            v1 = (v1 > 0.f) ? v1 : (__expf(v1) - 1.f);
            ow[p] = (unsigned)f2bf(v0) | ((unsigned)f2bf(v1) << 16);
        }
        *(uint4*)&h1act[(size_t)node * 128 + c0] = make_uint4(ow[0], ow[1], ow[2], ow[3]);
    }
}

// ---------------- GEMM2 (MFMA, persistent) + fused alpha2 --------------------
__global__ __launch_bounds__(256) void gemm2_kernel(
    const unsigned short* __restrict__ h1act, const float* __restrict__ W2,
    const float* __restrict__ a_s, const float* __restrict__ a_d,
    unsigned short* __restrict__ h2g, float* __restrict__ as_n,
    float* __restrict__ ad_n, int N) {
    __shared__ short Wt[64 * 136];
    int t = threadIdx.x;
    for (int id = t; id < 128 * 16; id += 256) {
        int k = id >> 4;
        int n0 = (id & 15) * 4;
        float4 v = *(const float4*)&W2[k * 64 + n0];
        Wt[(n0 + 0) * 136 + k] = (short)f2bf(v.x);
        Wt[(n0 + 1) * 136 + k] = (short)f2bf(v.y);
        Wt[(n0 + 2) * 136 + k] = (short)f2bf(v.z);
        Wt[(n0 + 3) * 136 + k] = (short)f2bf(v.w);
    }
    __syncthreads();
    int wv = t >> 6, lane = t & 63;
    int m = lane & 15, q = lane >> 4;
    float asl[4], adl[4];
#pragma unroll
    for (int j = 0; j < 4; j++) { asl[j] = a_s[j * 16 + m]; adl[j] = a_d[j * 16 + m]; }
    int T = (N + 63) >> 6;
    for (int tile = blockIdx.x; tile < T; tile += G2) {
        int row = tile * 64 + wv * 16 + m;
        f32x4 acc[4];
#pragma unroll
        for (int j = 0; j < 4; j++) acc[j] = (f32x4){0.f, 0.f, 0.f, 0.f};
#pragma unroll
        for (int k0 = 0; k0 < 128; k0 += 32) {
            bf16x8 a = {0, 0, 0, 0, 0, 0, 0, 0};
            if (row < N) a = *(const bf16x8*)&h1act[(size_t)row * 128 + k0 + q * 8];
#pragma unroll
            for (int j = 0; j < 4; j++) {
                bf16x8 b = *(const bf16x8*)&Wt[(j * 16 + m) * 136 + k0 + q * 8];
                acc[j] = __builtin_amdgcn_mfma_f32_16x16x32_bf16(a, b, acc[j], 0, 0, 0);
            }
        }
        int rbase = tile * 64 + wv * 16 + q * 4;
#pragma unroll
        for (int r = 0; r < 4; r++) {
            int rr = rbase + r;
            float s = 0.f, d = 0.f;
#pragma unroll
            for (int j = 0; j < 4; j++) {
                s += acc[j][r] * asl[j];
                d += acc[j][r] * adl[j];
            }
#pragma unroll
            for (int msk = 8; msk > 0; msk >>= 1) {
                s += __shfl_xor(s, msk, 64);
                d += __shfl_xor(d, msk, 64);
            }
            if (rr < N) {
                if (m == 0) { as_n[rr] = s; ad_n[rr] = d; }
#pragma unroll
                for (int j = 0; j < 4; j++)
                    h2g[(size_t)rr * 64 + j * 16 + m] = f2bf(acc[j][r]);
            }
        }
    }
}

// ---------------- layer-2 aggregation + log_softmax: wave/node ---------------
__global__ __launch_bounds__(256) void agg2_kernel(
    const int* __restrict__ row_start, const int* __restrict__ sorted_src,
    const float* __restrict__ as_n, const float* __restrict__ ad_n,
    const unsigned short* __restrict__ h2g, const float* __restrict__ b2,
    float* __restrict__ out, int N) {
    int node = blockIdx.x * 4 + (threadIdx.x >> 6);
    int lane = threadIdx.x & 63;
    if (node >= N) return;
    int slot = lane >> 4, cg = lane & 15;
    int e8 = lane & 7;
    float adv = ad_n[node];
    int beg = row_start[node], end = row_start[node + 1];
    float acc[4];
#pragma unroll
    for (int k = 0; k < 4; k++) acc[k] = 0.f;
    float denom = 0.f;
    for (int i = beg; i < end; i += 8) {
        int se = sorted_src[i + e8];
        float w = __expf(lrelu(as_n[se] + adv));
        w = (i + e8 < end) ? w : 0.f;
        float wva = __shfl(w, slot, 64);
        float wvb = __shfl(w, slot + 4, 64);
        int sga = __shfl(se, slot, 64);
        int sgb = __shfl(se, slot + 4, 64);
        uint2 hva = *(const uint2*)&h2g[(size_t)sga * 64 + cg * 4];
        uint2 hvb = *(const uint2*)&h2g[(size_t)sgb * 64 + cg * 4];
        acc[0] += wva * bf2f(hva.x & 0xffffu) + wvb * bf2f(hvb.x & 0xffffu);
        acc[1] += wva * bf2f(hva.x >> 16)     + wvb * bf2f(hvb.x >> 16);
        acc[2] += wva * bf2f(hva.y & 0xffffu) + wvb * bf2f(hvb.y & 0xffffu);
        acc[3] += wva * bf2f(hva.y >> 16)     + wvb * bf2f(hvb.y >> 16);
        denom += wva + wvb;
    }
#pragma unroll
    for (int msk = 16; msk < 64; msk <<= 1) {
#pragma unroll
        for (int k = 0; k < 4; k++) acc[k] += __shfl_xor(acc[k], msk, 64);
        denom += __shfl_xor(denom, msk, 64);
    }
    if (slot == 0) {
        float inv = 1.f / (denom + 1e-16f);
        int c0 = cg * 4;
        float v[4];
#pragma unroll
        for (int k = 0; k < 4; k++) v[k] = acc[k] * inv + b2[c0 + k];
        float m = fmaxf(fmaxf(v[0], v[1]), fmaxf(v[2], v[3]));
#pragma unroll
        for (int msk = 8; msk > 0; msk >>= 1) m = fmaxf(m, __shfl_xor(m, msk, 64));
        float ex = __expf(v[0] - m) + __expf(v[1] - m) + __expf(v[2] - m) + __expf(v[3] - m);
#pragma unroll
        for (int msk = 8; msk > 0; msk >>= 1) ex += __shfl_xor(ex, msk, 64);
        float lse = m + __logf(ex);
        float4 ov = make_float4(v[0] - lse, v[1] - lse, v[2] - lse, v[3] - lse);
        *(float4*)&out[(size_t)node * 64 + c0] = ov;
    }
}

extern "C" void kernel_launch(void* const* d_in, const int* in_sizes, int n_in,
                              void* d_out, int out_size, void* d_ws, size_t ws_size,
                              hipStream_t stream) {
    const float* x   = (const float*)d_in[0];
    const int*   idx = (const int*)d_in[1];
    const float* W1  = (const float*)d_in[2];
    const float* as1 = (const float*)d_in[3];
    const float* ad1 = (const float*)d_in[4];
    const float* b1  = (const float*)d_in[5];
    const float* W2  = (const float*)d_in[6];
    const float* as2 = (const float*)d_in[7];
    const float* ad2 = (const float*)d_in[8];
    const float* b2  = (const float*)d_in[9];
    float* out = (float*)d_out;

    const int N = in_sizes[0] / IN_DIM;
    const int E = in_sizes[1] / 2;
    const int EN = E + N;
    const int NB = (N + (1 << BSHIFT) - 1) >> BSHIFT;   // buckets
    const int GS = (EN + 256 * EPT - 1) / (256 * EPT);  // bscatter blocks
    const int A1 = (N * 8 + 255) / 256;                  // alpha1 blocks

    // workspace layout
    unsigned short* h1g   = (unsigned short*)d_ws;          // N*128 bf16
    unsigned short* h1act = h1g + (size_t)N * 128;          // N*128 bf16
    unsigned short* h2g   = h1act + (size_t)N * 128;        // N*64 bf16
    float* as1n = (float*)(h2g + (size_t)N * 64);           // N*8
    float* ad1n = as1n + (size_t)N * 8;                     // N*8
    float* as2n = ad1n + (size_t)N * 8;                     // N
    float* ad2n = as2n + (size_t)N;                         // N
    int* row_start  = (int*)(ad2n + (size_t)N);             // N+1
    int* gcursor    = row_start + N + 1;                    // 512
    unsigned* bucket_buf = (unsigned*)(gcursor + 512);      // NB*BCAP
    int* sorted_src = (int*)(bucket_buf + ((size_t)NB << BCAPSHIFT));  // E+N+8 (padded)
    (void)ws_size; (void)n_in; (void)out_size;

    hipMemsetAsync(gcursor, 0, 512 * sizeof(int), stream);

    k1_kernel<<<GS + G1, 256, 0, stream>>>(idx, gcursor, bucket_buf,
                                           x, W1, h1g, E, N, NB, GS);
    k2_kernel<<<NB + A1, 256, 0, stream>>>(gcursor, bucket_buf, row_start, sorted_src,
                                           h1g, as1, ad1, as1n, ad1n, N, NB, EN);
    agg1_kernel<<<(N + 3) / 4, 256, 0, stream>>>(row_start, sorted_src, as1n, ad1n, h1g, b1, h1act, N);
    gemm2_kernel<<<G2, 256, 0, stream>>>(h1act, W2, as2, ad2, h2g, as2n, ad2n, N);
    agg2_kernel<<<(N + 3) / 4, 256, 0, stream>>>(row_start, sorted_src, as2n, ad2n, h2g, b2, out, N);
}

// Round 10
// 210.814 us; speedup vs baseline: 1.0367x; 1.0236x over previous
//
#include <hip/hip_runtime.h>
#include <hip/hip_bf16.h>
#include <math.h>

#define IN_DIM 128
#define HID 128
#define HEADS 8
#define OUT_DIM 64
#define SLOPE 0.2f
#define BSHIFT 7          // 128 nodes per bucket
#define BCAP 4096         // entries per bucket (mean ~2176)
#define BCAPSHIFT 12
#define EPT 8             // edges per thread in bscatter

typedef short bf16x8 __attribute__((ext_vector_type(8)));
typedef float f32x4 __attribute__((ext_vector_type(4)));

__device__ __forceinline__ float lrelu(float x) { return fmaxf(x, SLOPE * x); }
__device__ __forceinline__ float bf2f(unsigned u) { return __uint_as_float(u << 16); }
__device__ __forceinline__ unsigned short f2bf(float f) {
    unsigned u = __float_as_uint(f);
    return (unsigned short)((u + 0x7FFF + ((u >> 16) & 1)) >> 16);  // RNE
}

// ---------------- K1 path A: bucket scatter with block-local counting sort ---
__device__ __forceinline__ void bscatter_body(
    int blk, int* smem, const int* __restrict__ idx,
    int* __restrict__ gcursor, unsigned* __restrict__ bucket_buf,
    int E, int N, int NB) {
    int* hist  = smem;
    int* gbase = smem + 512;
    int* lbase = smem + 1024;
    int* wtot  = smem + 1536;
    int* misc  = smem + 1540;     // [0]=total, [1]=nz
    unsigned* sent = (unsigned*)(smem + 1552);
    unsigned* spos = (unsigned*)(smem + 3600);
    int t = threadIdx.x;
    for (int i = t; i < 512; i += 256) hist[i] = 0;
    if (t == 0) misc[1] = 0;
    __syncthreads();
    {   // inline dtype detection: odd int32 words nonzero => int32 storage
        int nz = (idx[2 * t + 1] != 0) + (idx[2 * t + 513] != 0);
        if (nz) atomicAdd(&misc[1], nz);
    }
    __syncthreads();
    int flag = (misc[1] > 16) ? 1 : 0;   // 1 => int32, 0 => int64 storage
    int e0 = blk * (256 * EPT);
    int EN = E + N;
    unsigned ent[EPT];
    int bid[EPT];
    int loc[EPT];
#pragma unroll
    for (int k = 0; k < EPT; k++) {
        int e = e0 + k * 256 + t;
        bid[k] = -1;
        if (e < EN) {
            int src, dst;
            if (e < E) {
                if (flag) { src = idx[e]; dst = idx[E + e]; }
                else      { src = idx[2 * e]; dst = idx[2 * (E + e)]; }
            } else {
                src = dst = e - E;
            }
            int b = dst >> BSHIFT;
            bid[k] = b;
            ent[k] = ((unsigned)(dst & ((1 << BSHIFT) - 1)) << 16) | (unsigned)src;
            loc[k] = atomicAdd(&hist[b], 1);
        }
    }
    __syncthreads();
    // exclusive scan of hist[0..512): 256 threads x 2 consecutive elements
    int i0 = 2 * t;
    int a = hist[i0], b2 = hist[i0 + 1];
    int ps = a + b2;
    int lane = t & 63, w = t >> 6;
    int incl = ps;
#pragma unroll
    for (int off = 1; off < 64; off <<= 1) {
        int u = __shfl_up(incl, off, 64);
        if (lane >= off) incl += u;
    }
    if (lane == 63) wtot[w] = incl;
    __syncthreads();
    int woff = 0;
    for (int k = 0; k < w; k++) woff += wtot[k];
    int ex0 = woff + incl - ps;
    lbase[i0] = ex0;
    lbase[i0 + 1] = ex0 + a;
    if (t == 255) misc[0] = woff + incl;
    for (int i = t; i < 512; i += 256) {
        int c = hist[i];
        gbase[i] = c ? atomicAdd(&gcursor[i], c) : 0;
    }
    __syncthreads();
#pragma unroll
    for (int k = 0; k < EPT; k++) {
        if (bid[k] >= 0) {
            int p = lbase[bid[k]] + loc[k];
            int pib = gbase[bid[k]] + loc[k];
            sent[p] = ent[k];
            spos[p] = (pib < BCAP) ? (((unsigned)bid[k] << BCAPSHIFT) | (unsigned)pib)
                                   : 0xFFFFFFFFu;
        }
    }
    __syncthreads();
    int tot = misc[0];
    for (int i = t; i < tot; i += 256) {
        unsigned sp = spos[i];
        if (sp != 0xFFFFFFFFu) bucket_buf[sp] = sent[i];
    }
}

// ---------------- K1 path B: MFMA GEMM1 (one tile per block) -----------------
__device__ __forceinline__ void gemm1_body(
    int blk, short* Wt, const float* __restrict__ x, const float* __restrict__ W1,
    unsigned short* __restrict__ h1g, int N) {
    int t = threadIdx.x;
    for (int id = t; id < 128 * 32; id += 256) {       // stage W1 -> Wt[n][k], pad 136
        int k = id >> 5;
        int n0 = (id & 31) * 4;
        float4 v = *(const float4*)&W1[k * 128 + n0];
        Wt[(n0 + 0) * 136 + k] = (short)f2bf(v.x);
        Wt[(n0 + 1) * 136 + k] = (short)f2bf(v.y);
        Wt[(n0 + 2) * 136 + k] = (short)f2bf(v.z);
        Wt[(n0 + 3) * 136 + k] = (short)f2bf(v.w);
    }
    __syncthreads();
    int wv = t >> 6, lane = t & 63;
    int m = lane & 15, q = lane >> 4;
    int row = blk * 64 + wv * 16 + m;
    f32x4 acc[8];
#pragma unroll
    for (int j = 0; j < 8; j++) acc[j] = (f32x4){0.f, 0.f, 0.f, 0.f};
#pragma unroll
    for (int k0 = 0; k0 < 128; k0 += 32) {
        bf16x8 a = {0, 0, 0, 0, 0, 0, 0, 0};
        if (row < N) {
            const float* xp = &x[(size_t)row * 128 + k0 + q * 8];
            float4 u0 = *(const float4*)xp;
            float4 u1 = *(const float4*)(xp + 4);
            a[0] = (short)f2bf(u0.x); a[1] = (short)f2bf(u0.y);
            a[2] = (short)f2bf(u0.z); a[3] = (short)f2bf(u0.w);
            a[4] = (short)f2bf(u1.x); a[5] = (short)f2bf(u1.y);
            a[6] = (short)f2bf(u1.z); a[7] = (short)f2bf(u1.w);
        }
#pragma unroll
        for (int j = 0; j < 8; j++) {
            bf16x8 b = *(const bf16x8*)&Wt[(j * 16 + m) * 136 + k0 + q * 8];
            acc[j] = __builtin_amdgcn_mfma_f32_16x16x32_bf16(a, b, acc[j], 0, 0, 0);
        }
    }
    int rbase = blk * 64 + wv * 16 + q * 4;
#pragma unroll
    for (int r = 0; r < 4; r++) {
        int rr = rbase + r;
        if (rr < N) {
#pragma unroll
            for (int j = 0; j < 8; j++)
                h1g[(size_t)rr * 128 + j * 16 + m] = f2bf(acc[j][r]);
        }
    }
}

__global__ __launch_bounds__(256) void k1_kernel(
    const int* __restrict__ idx, int* __restrict__ gcursor,
    unsigned* __restrict__ bucket_buf,
    const float* __restrict__ x, const float* __restrict__ W1,
    unsigned short* __restrict__ h1g, int E, int N, int NB, int GS) {
    __shared__ long long smem[4352];   // union: Wt (34816 B) | bscatter (22.6 KB)
    if ((int)blockIdx.x < GS)
        bscatter_body(blockIdx.x, (int*)smem, idx, gcursor, bucket_buf, E, N, NB);
    else
        gemm1_body(blockIdx.x - GS, (short*)smem, x, W1, h1g, N);
}

// ---------------- K2 path A: per-bucket sort, LDS-staged coalesced flush -----
__device__ __forceinline__ void bsort_body(
    int b, const int* __restrict__ gcursor, const unsigned* __restrict__ bucket_buf,
    int* __restrict__ row_start, int* __restrict__ sorted_src, int N, int NB) {
    __shared__ int cnt[128];
    __shared__ int cur[128];
    __shared__ int red[4];
    __shared__ int s_w0;
    __shared__ int srt[BCAP];
    int t = threadIdx.x;
    if (t < 128) cnt[t] = 0;
    int partial = 0;
    for (int i = t; i < b; i += 256) partial += min(gcursor[i], BCAP);
#pragma unroll
    for (int msk = 32; msk > 0; msk >>= 1) partial += __shfl_xor(partial, msk, 64);
    if ((t & 63) == 0) red[t >> 6] = partial;
    __syncthreads();
    int bbase = red[0] + red[1] + red[2] + red[3];
    int c = min(gcursor[b], BCAP);
    const unsigned* buf = bucket_buf + ((size_t)b << BCAPSHIFT);
    for (int i = t; i < c; i += 256)
        atomicAdd(&cnt[(buf[i] >> 16) & 127], 1);
    __syncthreads();
    int v = (t < 128) ? cnt[t] : 0;
    int lane = t & 63;
    int incl = v;
#pragma unroll
    for (int off = 1; off < 64; off <<= 1) {
        int u = __shfl_up(incl, off, 64);
        if (lane >= off) incl += u;
    }
    if (t == 63) s_w0 = incl;
    __syncthreads();
    if (t < 128) {
        int excl = incl - v + ((t >= 64) ? s_w0 : 0);
        cur[t] = excl;
        int node = (b << BSHIFT) + t;
        if (node <= N) row_start[node] = bbase + excl;
    }
    __syncthreads();
    for (int i = t; i < c; i += 256) {
        unsigned e = buf[i];
        int lp = atomicAdd(&cur[(e >> 16) & 127], 1);
        srt[lp] = (int)(e & 0xFFFFu);
    }
    __syncthreads();
    for (int i = t; i < c; i += 256)
        sorted_src[bbase + i] = srt[i];     // coalesced flush
}

// ---------------- K2 path B: alpha1 ------------------------------------------
__device__ __forceinline__ void alpha1_body(
    int blk, const unsigned short* __restrict__ h1g,
    const float* __restrict__ a_s, const float* __restrict__ a_d,
    float* __restrict__ as_n, float* __restrict__ ad_n, int N) {
    int gid = blk * 256 + threadIdx.x;
    if (gid >= N * 8) return;
    int n = gid >> 3, hd = gid & 7;
    const uint4* hp = (const uint4*)(h1g + (size_t)n * 128 + hd * 16);
    uint4 u0 = hp[0], u1 = hp[1];
    unsigned uu[8] = {u0.x, u0.y, u0.z, u0.w, u1.x, u1.y, u1.z, u1.w};
    const float* sp = a_s + hd * 16;
    const float* dp = a_d + hd * 16;
    float s = 0.f, d = 0.f;
#pragma unroll
    for (int k = 0; k < 8; k++) {
        float lo = bf2f(uu[k] & 0xffffu), hi = bf2f(uu[k] >> 16);
        s += lo * sp[2 * k] + hi * sp[2 * k + 1];
        d += lo * dp[2 * k] + hi * dp[2 * k + 1];
    }
    as_n[gid] = s;
    ad_n[gid] = d;
}

__global__ __launch_bounds__(256) void k2_kernel(
    const int* __restrict__ gcursor, const unsigned* __restrict__ bucket_buf,
    int* __restrict__ row_start, int* __restrict__ sorted_src,
    const unsigned short* __restrict__ h1g,
    const float* __restrict__ a_s, const float* __restrict__ a_d,
    float* __restrict__ as_n, float* __restrict__ ad_n, int N, int NB, int EN) {
    if (blockIdx.x == 0 && threadIdx.x < 16) sorted_src[EN + threadIdx.x] = 0;  // pad
    if ((int)blockIdx.x < NB)
        bsort_body(blockIdx.x, gcursor, bucket_buf, row_start, sorted_src, N, NB);
    else
        alpha1_body(blockIdx.x - NB, h1g, a_s, a_d, as_n, ad_n, N);
}

// ---------------- layer-1 aggregation: wave/node, 16 edges/iter --------------
__global__ __launch_bounds__(256) void agg1_kernel(
    const int* __restrict__ row_start, const int* __restrict__ sorted_src,
    const float* __restrict__ as_n, const float* __restrict__ ad_n,
    const unsigned short* __restrict__ h1g, const float* __restrict__ b1,
    unsigned short* __restrict__ h1act, int N) {
    int node = blockIdx.x * 4 + (threadIdx.x >> 6);
    int lane = threadIdx.x & 63;
    if (node >= N) return;
    int slot = lane >> 4, cg = lane & 15;
    int e8 = lane >> 3, hd8 = lane & 7;
    int wl_a = (slot << 3) | (cg >> 1);
    int wl_b = ((slot + 4) << 3) | (cg >> 1);
    float ad_w = ad_n[node * 8 + hd8];
    int beg = row_start[node], end = row_start[node + 1];
    float acc[8];
#pragma unroll
    for (int k = 0; k < 8; k++) acc[k] = 0.f;
    float denom = 0.f;
    for (int i = beg; i < end; i += 16) {
        int se1 = sorted_src[i + e8];
        int se2 = sorted_src[i + 8 + e8];
        float w1 = __expf(lrelu(as_n[se1 * 8 + hd8] + ad_w));
        float w2 = __expf(lrelu(as_n[se2 * 8 + hd8] + ad_w));
        w1 = (i + e8 < end) ? w1 : 0.f;
        w2 = (i + 8 + e8 < end) ? w2 : 0.f;
        float wva = __shfl(w1, wl_a, 64);
        float wvb = __shfl(w1, wl_b, 64);
        float wvc = __shfl(w2, wl_a, 64);
        float wvd = __shfl(w2, wl_b, 64);
        int sga = __shfl(se1, wl_a, 64);
        int sgb = __shfl(se1, wl_b, 64);
        int sgc = __shfl(se2, wl_a, 64);
        int sgd = __shfl(se2, wl_b, 64);
        uint4 hva = *(const uint4*)&h1g[(size_t)sga * 128 + cg * 8];
        uint4 hvb = *(const uint4*)&h1g[(size_t)sgb * 128 + cg * 8];
        uint4 hvc = *(const uint4*)&h1g[(size_t)sgc * 128 + cg * 8];
        uint4 hvd = *(const uint4*)&h1g[(size_t)sgd * 128 + cg * 8];
        acc[0] += wva * bf2f(hva.x & 0xffffu) + wvb * bf2f(hvb.x & 0xffffu)
                + wvc * bf2f(hvc.x & 0xffffu) + wvd * bf2f(hvd.x & 0xffffu);
        acc[1] += wva * bf2f(hva.x >> 16) + wvb * bf2f(hvb.x >> 16)
                + wvc * bf2f(hvc.x >> 16) + wvd * bf2f(hvd.x >> 16);
        acc[2] += wva * bf2f(hva.y & 0xffffu) + wvb * bf2f(hvb.y & 0xffffu)
                + wvc * bf2f(hvc.y & 0xffffu) + wvd * bf2f(hvd.y & 0xffffu);
        acc[3] += wva * bf2f(hva.y >> 16) + wvb * bf2f(hvb.y >> 16)
                + wvc * bf2f(hvc.y >> 16) + wvd * bf2f(hvd.y >> 16);
        acc[4] += wva * bf2f(hva.z & 0xffffu) + wvb * bf2f(hvb.z & 0xffffu)
                + wvc * bf2f(hvc.z & 0xffffu) + wvd * bf2f(hvd.z & 0xffffu);
        acc[5] += wva * bf2f(hva.z >> 16) + wvb * bf2f(hvb.z >> 16)
                + wvc * bf2f(hvc.z >> 16) + wvd * bf2f(hvd.z >> 16);
        acc[6] += wva * bf2f(hva.w & 0xffffu) + wvb * bf2f(hvb.w & 0xffffu)
                + wvc * bf2f(hvc.w & 0xffffu) + wvd * bf2f(hvd.w & 0xffffu);
        acc[7] += wva * bf2f(hva.w >> 16) + wvb * bf2f(hvb.w >> 16)
                + wvc * bf2f(hvc.w >> 16) + wvd * bf2f(hvd.w >> 16);
        denom += wva + wvb + wvc + wvd;
    }
#pragma unroll
    for (int msk = 16; msk < 64; msk <<= 1) {
#pragma unroll
        for (int k = 0; k < 8; k++) acc[k] += __shfl_xor(acc[k], msk, 64);
        denom += __shfl_xor(denom, msk, 64);
    }
    if (slot == 0) {
        float inv = 1.f / (denom + 1e-16f);
        int c0 = cg * 8;
        unsigned ow[4];
#pragma unroll
        for (int p = 0; p < 4; p++) {
            float v0 = acc[2 * p] * inv + b1[c0 + 2 * p];
            float v1 = acc[2 * p + 1] * inv + b1[c0 + 2 * p + 1];
            v0 = (v0 > 0.f) ? v0 : (__expf(v0) - 1.f);
            v1 = (v1 > 0.f) ? v1 : (__expf(v1) - 1.f);
            ow[p] = (unsigned)f2bf(v0) | ((unsigned)f2bf(v1) << 16);
        }
        *(uint4*)&h1act[(size_t)node * 128 + c0] = make_uint4(ow[0], ow[1], ow[2], ow[3]);
    }
}

// ---------------- GEMM2 (MFMA, per-tile) + fused alpha2 ----------------------
__global__ __launch_bounds__(256) void gemm2_kernel(
    const unsigned short* __restrict__ h1act, const float* __restrict__ W2,
    const float* __restrict__ a_s, const float* __restrict__ a_d,
    unsigned short* __restrict__ h2g, float* __restrict__ as_n,
    float* __restrict__ ad_n, int N) {
    __shared__ short Wt[64 * 136];
    int t = threadIdx.x;
    for (int id = t; id < 128 * 16; id += 256) {
        int k = id >> 4;
        int n0 = (id & 15) * 4;
        float4 v = *(const float4*)&W2[k * 64 + n0];
        Wt[(n0 + 0) * 136 + k] = (short)f2bf(v.x);
        Wt[(n0 + 1) * 136 + k] = (short)f2bf(v.y);
        Wt[(n0 + 2) * 136 + k] = (short)f2bf(v.z);
        Wt[(n0 + 3) * 136 + k] = (short)f2bf(v.w);
    }
    __syncthreads();
    int wv = t >> 6, lane = t & 63;
    int m = lane & 15, q = lane >> 4;
    int row = blockIdx.x * 64 + wv * 16 + m;
    f32x4 acc[4];
#pragma unroll
    for (int j = 0; j < 4; j++) acc[j] = (f32x4){0.f, 0.f, 0.f, 0.f};
#pragma unroll
    for (int k0 = 0; k0 < 128; k0 += 32) {
        bf16x8 a = {0, 0, 0, 0, 0, 0, 0, 0};
        if (row < N) a = *(const bf16x8*)&h1act[(size_t)row * 128 + k0 + q * 8];
#pragma unroll
        for (int j = 0; j < 4; j++) {
            bf16x8 b = *(const bf16x8*)&Wt[(j * 16 + m) * 136 + k0 + q * 8];
            acc[j] = __builtin_amdgcn_mfma_f32_16x16x32_bf16(a, b, acc[j], 0, 0, 0);
        }
    }
    float asl[4], adl[4];
#pragma unroll
    for (int j = 0; j < 4; j++) { asl[j] = a_s[j * 16 + m]; adl[j] = a_d[j * 16 + m]; }
    int rbase = blockIdx.x * 64 + wv * 16 + q * 4;
#pragma unroll
    for (int r = 0; r < 4; r++) {
        int rr = rbase + r;
        float s = 0.f, d = 0.f;
#pragma unroll
        for (int j = 0; j < 4; j++) {
            s += acc[j][r] * asl[j];
            d += acc[j][r] * adl[j];
        }
#pragma unroll
        for (int msk = 8; msk > 0; msk >>= 1) {
            s += __shfl_xor(s, msk, 64);
            d += __shfl_xor(d, msk, 64);
        }
        if (rr < N) {
            if (m == 0) { as_n[rr] = s; ad_n[rr] = d; }
#pragma unroll
            for (int j = 0; j < 4; j++)
                h2g[(size_t)rr * 64 + j * 16 + m] = f2bf(acc[j][r]);
        }
    }
}

// ---------------- layer-2 aggregation + log_softmax: 16 edges/iter -----------
__global__ __launch_bounds__(256) void agg2_kernel(
    const int* __restrict__ row_start, const int* __restrict__ sorted_src,
    const float* __restrict__ as_n, const float* __restrict__ ad_n,
    const unsigned short* __restrict__ h2g, const float* __restrict__ b2,
    float* __restrict__ out, int N) {
    int node = blockIdx.x * 4 + (threadIdx.x >> 6);
    int lane = threadIdx.x & 63;
    if (node >= N) return;
    int slot = lane >> 4, cg = lane & 15;
    int e8 = lane & 7;
    float adv = ad_n[node];
    int beg = row_start[node], end = row_start[node + 1];
    float acc[4];
#pragma unroll
    for (int k = 0; k < 4; k++) acc[k] = 0.f;
    float denom = 0.f;
    for (int i = beg; i < end; i += 16) {
        int se1 = sorted_src[i + e8];
        int se2 = sorted_src[i + 8 + e8];
        float w1 = __expf(lrelu(as_n[se1] + adv));
        float w2 = __expf(lrelu(as_n[se2] + adv));
        w1 = (i + e8 < end) ? w1 : 0.f;
        w2 = (i + 8 + e8 < end) ? w2 : 0.f;
        float wva = __shfl(w1, slot, 64);
        float wvb = __shfl(w1, slot + 4, 64);
        float wvc = __shfl(w2, slot, 64);
        float wvd = __shfl(w2, slot + 4, 64);
        int sga = __shfl(se1, slot, 64);
        int sgb = __shfl(se1, slot + 4, 64);
        int sgc = __shfl(se2, slot, 64);
        int sgd = __shfl(se2, slot + 4, 64);
        uint2 hva = *(const uint2*)&h2g[(size_t)sga * 64 + cg * 4];
        uint2 hvb = *(const uint2*)&h2g[(size_t)sgb * 64 + cg * 4];
        uint2 hvc = *(const uint2*)&h2g[(size_t)sgc * 64 + cg * 4];
        uint2 hvd = *(const uint2*)&h2g[(size_t)sgd * 64 + cg * 4];
        acc[0] += wva * bf2f(hva.x & 0xffffu) + wvb * bf2f(hvb.x & 0xffffu)
                + wvc * bf2f(hvc.x & 0xffffu) + wvd * bf2f(hvd.x & 0xffffu);
        acc[1] += wva * bf2f(hva.x >> 16) + wvb * bf2f(hvb.x >> 16)
                + wvc * bf2f(hvc.x >> 16) + wvd * bf2f(hvd.x >> 16);
        acc[2] += wva * bf2f(hva.y & 0xffffu) + wvb * bf2f(hvb.y & 0xffffu)
                + wvc * bf2f(hvc.y & 0xffffu) + wvd * bf2f(hvd.y & 0xffffu);
        acc[3] += wva * bf2f(hva.y >> 16) + wvb * bf2f(hvb.y >> 16)
                + wvc * bf2f(hvc.y >> 16) + wvd * bf2f(hvd.y >> 16);
        denom += wva + wvb + wvc + wvd;
    }
#pragma unroll
    for (int msk = 16; msk < 64; msk <<= 1) {
#pragma unroll
        for (int k = 0; k < 4; k++) acc[k] += __shfl_xor(acc[k], msk, 64);
        denom += __shfl_xor(denom, msk, 64);
    }
    if (slot == 0) {
        float inv = 1.f / (denom + 1e-16f);
        int c0 = cg * 4;
        float v[4];
#pragma unroll
        for (int k = 0; k < 4; k++) v[k] = acc[k] * inv + b2[c0 + k];
        float m = fmaxf(fmaxf(v[0], v[1]), fmaxf(v[2], v[3]));
#pragma unroll
        for (int msk = 8; msk > 0; msk >>= 1) m = fmaxf(m, __shfl_xor(m, msk, 64));
        float ex = __expf(v[0] - m) + __expf(v[1] - m) + __expf(v[2] - m) + __expf(v[3] - m);
#pragma unroll
        for (int msk = 8; msk > 0; msk >>= 1) ex += __shfl_xor(ex, msk, 64);
        float lse = m + __logf(ex);
        float4 ov = make_float4(v[0] - lse, v[1] - lse, v[2] - lse, v[3] - lse);
        *(float4*)&out[(size_t)node * 64 + c0] = ov;
    }
}

extern "C" void kernel_launch(void* const* d_in, const int* in_sizes, int n_in,
                              void* d_out, int out_size, void* d_ws, size_t ws_size,
                              hipStream_t stream) {
    const float* x   = (const float*)d_in[0];
    const int*   idx = (const int*)d_in[1];
    const float* W1  = (const float*)d_in[2];
    const float* as1 = (const float*)d_in[3];
    const float* ad1 = (const float*)d_in[4];
    const float* b1  = (const float*)d_in[5];
    const float* W2  = (const float*)d_in[6];
    const float* as2 = (const float*)d_in[7];
    const float* ad2 = (const float*)d_in[8];
    const float* b2  = (const float*)d_in[9];
    float* out = (float*)d_out;

    const int N = in_sizes[0] / IN_DIM;
    const int E = in_sizes[1] / 2;
    const int EN = E + N;
    const int NB = (N + (1 << BSHIFT) - 1) >> BSHIFT;   // buckets
    const int GS = (EN + 256 * EPT - 1) / (256 * EPT);  // bscatter blocks
    const int A1 = (N * 8 + 255) / 256;                  // alpha1 blocks
    const int T1 = (N + 63) / 64;                        // gemm tiles

    // workspace layout
    unsigned short* h1g   = (unsigned short*)d_ws;          // N*128 bf16
    unsigned short* h1act = h1g + (size_t)N * 128;          // N*128 bf16
    unsigned short* h2g   = h1act + (size_t)N * 128;        // N*64 bf16
    float* as1n = (float*)(h2g + (size_t)N * 64);           // N*8
    float* ad1n = as1n + (size_t)N * 8;                     // N*8
    float* as2n = ad1n + (size_t)N * 8;                     // N
    float* ad2n = as2n + (size_t)N;                         // N
    int* row_start  = (int*)(ad2n + (size_t)N);             // N+1
    int* gcursor    = row_start + N + 1;                    // 512
    unsigned* bucket_buf = (unsigned*)(gcursor + 512);      // NB*BCAP
    int* sorted_src = (int*)(bucket_buf + ((size_t)NB << BCAPSHIFT));  // E+N+16 (padded)
    (void)ws_size; (void)n_in; (void)out_size;

    hipMemsetAsync(gcursor, 0, 512 * sizeof(int), stream);

    k1_kernel<<<GS + T1, 256, 0, stream>>>(idx, gcursor, bucket_buf,
                                           x, W1, h1g, E, N, NB, GS);
    k2_kernel<<<NB + A1, 256, 0, stream>>>(gcursor, bucket_buf, row_start, sorted_src,
                                           h1g, as1, ad1, as1n, ad1n, N, NB, EN);
    agg1_kernel<<<(N + 3) / 4, 256, 0, stream>>>(row_start, sorted_src, as1n, ad1n, h1g, b1, h1act, N);
    gemm2_kernel<<<T1, 256, 0, stream>>>(h1act, W2, as2, ad2, h2g, as2n, ad2n, N);
    agg2_kernel<<<(N + 3) / 4, 256, 0, stream>>>(row_start, sorted_src, as2n, ad2n, h2g, b2, out, N);
}